// Round 11
// baseline (474.568 us; speedup 1.0000x reference)
//
#include <hip/hip_runtime.h>

#define IN_DIM 256
#define HID 64
#define K_ITERS 10
#define ALPHA 0.1f

constexpr int RPB      = 128;   // rows per bucket (bucket = row >> 7)
constexpr int BCAP     = 4992;  // slots per bucket; counts ~Poisson(4096)
constexpr int OVF_CAP  = 8192;
constexpr int MAXBUCK  = 800;   // nbuck = 782 here
constexpr int CHUNK    = 12544; // edges per build block

typedef __attribute__((ext_vector_type(8))) short short8v;
typedef __attribute__((ext_vector_type(4))) float float4v;

__device__ __forceinline__ unsigned short f32_bf16(float f) {
  unsigned u = __float_as_uint(f);
  u += 0x7FFFu + ((u >> 16) & 1u);
  return (unsigned short)(u >> 16);
}
__device__ __forceinline__ float bf16_f32(unsigned short h) {
  return __uint_as_float((unsigned)h << 16);
}

// ---------------- W1 -> fragment-ordered bf16 hi/lo planes ----------------
__global__ __launch_bounds__(256) void w1_frag(
    const float* __restrict__ W1, unsigned short* __restrict__ W1F)
{
  int idx = blockIdx.x * 256 + threadIdx.x;   // 16384
  int i  = idx & 7;
  int ln = (idx >> 3) & 63;
  int ht = (idx >> 9) & 3;
  int ks = idx >> 11;
  int hid = ht * 16 + (ln & 15);
  int k   = ks * 32 + (ln >> 4) * 8 + i;
  float v = W1[hid * IN_DIM + k];
  unsigned short hi = f32_bf16(v);
  unsigned short lo = f32_bf16(v - bf16_f32(hi));
  W1F[idx]         = hi;
  W1F[16384 + idx] = lo;
}

// ---------------- MLP via split-bf16 MFMA (proven round 8) ----------------
__global__ __launch_bounds__(256) void mlp_mfma(
    const float* __restrict__ x, const unsigned short* __restrict__ W1F,
    const float* __restrict__ b1, const float* __restrict__ W2,
    const float* __restrict__ b2, float* __restrict__ Z, int n)
{
  const int tid  = threadIdx.x;
  const int w    = tid >> 6;
  const int lane = tid & 63;
  const int m    = lane & 15;
  const int kg   = lane >> 4;
  const int node = blockIdx.x * 64 + w * 16 + m;
  const bool valid = node < n;
  const float* xrow = x + (size_t)(valid ? node : 0) * IN_DIM;

  const short8v* Bhi = reinterpret_cast<const short8v*>(W1F);
  const short8v* Blo = Bhi + 2048;

  float4v acc[4];
  #pragma unroll
  for (int ht = 0; ht < 4; ++ht) acc[ht] = (float4v){0.f, 0.f, 0.f, 0.f};

  #pragma unroll
  for (int ks = 0; ks < 8; ++ks) {
    const int kb = ks * 32 + kg * 8;
    float4 a0 = *reinterpret_cast<const float4*>(xrow + kb);
    float4 a1 = *reinterpret_cast<const float4*>(xrow + kb + 4);
    float xv[8] = {a0.x, a0.y, a0.z, a0.w, a1.x, a1.y, a1.z, a1.w};
    short8v ahi, alo;
    #pragma unroll
    for (int i = 0; i < 8; ++i) {
      unsigned short h = f32_bf16(xv[i]);
      ahi[i] = (short)h;
      alo[i] = (short)f32_bf16(xv[i] - bf16_f32(h));
    }
    #pragma unroll
    for (int ht = 0; ht < 4; ++ht) {
      int bidx = (ks * 4 + ht) * 64 + lane;
      short8v bh = Bhi[bidx];
      short8v bl = Blo[bidx];
      acc[ht] = __builtin_amdgcn_mfma_f32_16x16x32_bf16(ahi, bh, acc[ht], 0, 0, 0);
      acc[ht] = __builtin_amdgcn_mfma_f32_16x16x32_bf16(alo, bh, acc[ht], 0, 0, 0);
      acc[ht] = __builtin_amdgcn_mfma_f32_16x16x32_bf16(ahi, bl, acc[ht], 0, 0, 0);
    }
  }

  float p0[4] = {0.f, 0.f, 0.f, 0.f}, p1[4] = {0.f, 0.f, 0.f, 0.f};
  #pragma unroll
  for (int ht = 0; ht < 4; ++ht) {
    int hid = ht * 16 + m;
    float w0 = W2[hid], w1v = W2[HID + hid], bb = b1[hid];
    #pragma unroll
    for (int j = 0; j < 4; ++j) {
      float h = fmaxf(acc[ht][j] + bb, 0.f);
      p0[j] = fmaf(h, w0, p0[j]);
      p1[j] = fmaf(h, w1v, p1[j]);
    }
  }
  #pragma unroll
  for (int j = 0; j < 4; ++j) {
    #pragma unroll
    for (int s = 1; s < 16; s <<= 1) {
      p0[j] += __shfl_xor(p0[j], s);
      p1[j] += __shfl_xor(p1[j], s);
    }
  }
  if (m == 0) {
    #pragma unroll
    for (int j = 0; j < 4; ++j) {
      int nd = blockIdx.x * 64 + w * 16 + kg * 4 + j;
      if (nd < n) {
        Z[(size_t)nd * 2 + 0] = p0[j] + b2[0];
        Z[(size_t)nd * 2 + 1] = p1[j] + b2[1];
      }
    }
  }
}

// ---------------- Bucket build v3: LDS-reordered, coalesced write-out ------
__global__ __launch_bounds__(512) void bucket_build2(
    const int* __restrict__ rows, const int* __restrict__ cols,
    const float* __restrict__ vals, int* __restrict__ gcnt,
    int2* __restrict__ binned, int4* __restrict__ ovf, int* __restrict__ ovfN,
    int e, int nbuck)
{
  __shared__ int2 buf[CHUNK];                 // 100.4 KB
  __shared__ unsigned short sb[CHUNK];        // 25.1 KB
  __shared__ int h1[MAXBUCK];
  __shared__ int scn[2][MAXBUCK];
  __shared__ int lofs[MAXBUCK];
  __shared__ int cur[MAXBUCK];
  __shared__ int gbase[MAXBUCK];

  const int tid = threadIdx.x;
  const int beg = blockIdx.x * CHUNK;
  const int end = min(beg + CHUNK, e);
  const int cnt = end - beg;

  for (int b = tid; b < nbuck; b += 512) h1[b] = 0;
  __syncthreads();

  for (int i = beg + tid; i < end; i += 512)
    atomicAdd(&h1[rows[i] >> 7], 1);
  __syncthreads();

  int p = 0;
  for (int b = tid; b < nbuck; b += 512) scn[0][b] = h1[b];
  __syncthreads();
  for (int off = 1; off < nbuck; off <<= 1) {
    for (int b = tid; b < nbuck; b += 512)
      scn[p ^ 1][b] = (b >= off) ? scn[p][b] + scn[p][b - off] : scn[p][b];
    __syncthreads();
    p ^= 1;
  }
  for (int b = tid; b < nbuck; b += 512) {
    int ex = (b == 0) ? 0 : scn[p][b - 1];
    lofs[b] = ex;
    cur[b]  = ex;
  }
  __syncthreads();

  for (int i = beg + tid; i < end; i += 512) {
    int r = rows[i];
    int b = r >> 7;
    int pos = atomicAdd(&cur[b], 1);
    buf[pos] = make_int2(((r & 127) << 17) | cols[i], __float_as_int(vals[i]));
    sb[pos]  = (unsigned short)b;
  }
  for (int b = tid; b < nbuck; b += 512)
    gbase[b] = h1[b] ? atomicAdd(&gcnt[b], h1[b]) : 0;
  __syncthreads();

  for (int i = tid; i < cnt; i += 512) {
    int b = sb[i];
    int pos = gbase[b] + (i - lofs[b]);
    int2 ed = buf[i];
    if (pos < BCAP) {
      binned[(size_t)b * BCAP + pos] = ed;
    } else {
      int k = atomicAdd(ovfN, 1);
      if (k < OVF_CAP) ovf[k] = make_int4(b, ed.x, ed.y, 0);
    }
  }
}

// ---------------- Row-sort each bucket + bucket-local CSR offsets ----------
__global__ __launch_bounds__(512) void bucket_sort(
    const int* __restrict__ gcnt, int2* __restrict__ binned,
    int* __restrict__ rowoff, int nbuck)
{
  __shared__ int2 buf[BCAP];
  __shared__ int hist[RPB];
  __shared__ int offs[RPB];
  __shared__ int cur[RPB];
  const int b = blockIdx.x, tid = threadIdx.x;
  const int cnt = min(gcnt[b], BCAP);
  int2* gp = binned + (size_t)b * BCAP;

  if (tid < RPB) hist[tid] = 0;
  __syncthreads();
  for (int i = tid; i < cnt; i += 512) {
    int2 e = gp[i];
    buf[i] = e;
    atomicAdd(&hist[e.x >> 17], 1);
  }
  __syncthreads();
  if (tid == 0) {
    int run = 0;
    for (int r = 0; r < RPB; ++r) { offs[r] = run; cur[r] = run; run += hist[r]; }
  }
  __syncthreads();
  if (tid < RPB) rowoff[b * RPB + tid] = offs[tid];
  for (int i = tid; i < cnt; i += 512) {
    int2 e = buf[i];
    int pos = atomicAdd(&cur[e.x >> 17], 1);
    gp[pos] = e;
  }
}

// ---------------- APPNP step: row-segment gather, nt edge stream -----------
// Edge-stream loads are non-temporal (evict-first in L2) so the 25.6 MB/iter
// stream doesn't evict the 800 KB H working set; random H reads stay L2-hits.
__global__ __launch_bounds__(256) void sorted_gather(
    const int* __restrict__ rowoff, const int* __restrict__ gcnt,
    const int2* __restrict__ binned, const float* __restrict__ Z,
    const float* __restrict__ Hin, float* __restrict__ Hout,
    const int4* __restrict__ ovf, const int* __restrict__ ovfN,
    float cB, int n)
{
  int g = blockIdx.x * 256 + threadIdx.x;
  int r = g >> 2, l = g & 3;
  if (r >= n) return;
  int b = r >> 7, rl = r & 127;
  int cntraw = gcnt[b];
  int cnt = min(cntraw, BCAP);
  int beg = rowoff[b * RPB + rl];
  int end = (rl == RPB - 1) ? cnt : rowoff[b * RPB + rl + 1];
  const long long* bp = reinterpret_cast<const long long*>(binned + (size_t)b * BCAP);
  float sx = 0.f, sy = 0.f;
  for (int i = beg + l; i < end; i += 4) {
    long long pe = __builtin_nontemporal_load(bp + i);   // nt: don't pollute L2
    int px = (int)(unsigned)(pe & 0xFFFFFFFFll);
    float v = __int_as_float((int)(pe >> 32));
    int col = px & 0x1FFFF;
    float2 h = *reinterpret_cast<const float2*>(&Hin[(size_t)col * 2]);
    sx = fmaf(v, h.x, sx); sy = fmaf(v, h.y, sy);
  }
  if (cntraw > BCAP) {
    int mo = min(*ovfN, OVF_CAP);
    for (int j = l; j < mo; j += 4) {
      int4 o = ovf[j];
      if (o.x == b && (o.y >> 17) == rl) {
        int col = o.y & 0x1FFFF;
        float v = __int_as_float(o.z);
        float2 h = *reinterpret_cast<const float2*>(&Hin[(size_t)col * 2]);
        sx += v * h.x; sy += v * h.y;
      }
    }
  }
  sx += __shfl_xor(sx, 1); sy += __shfl_xor(sy, 1);
  sx += __shfl_xor(sx, 2); sy += __shfl_xor(sy, 2);
  if (l == 0) {
    float2 z = *reinterpret_cast<const float2*>(&Z[(size_t)r * 2]);
    reinterpret_cast<float2*>(Hout)[r] =
        make_float2(ALPHA * z.x + cB * sx, ALPHA * z.y + cB * sy);
  }
}

extern "C" void kernel_launch(void* const* d_in, const int* in_sizes, int n_in,
                              void* d_out, int out_size, void* d_ws, size_t ws_size,
                              hipStream_t stream) {
  const float* x     = (const float*)d_in[0];
  const float* W1    = (const float*)d_in[1];
  const float* b1    = (const float*)d_in[2];
  const float* W2    = (const float*)d_in[3];
  const float* b2    = (const float*)d_in[4];
  const int*   erows = (const int*)d_in[5];
  const int*   ecols = (const int*)d_in[6];
  const float* evals = (const float*)d_in[7];
  float* out = (float*)d_out;

  const int n = in_sizes[0] / IN_DIM;     // 100000
  const int e = in_sizes[5];              // 3200000
  const int nbuck = (n + RPB - 1) / RPB;  // 782

  char* ws = (char*)d_ws;
  int2*  binned = (int2*)ws;            ws += (size_t)nbuck * BCAP * sizeof(int2);
  int4*  ovf    = (int4*)ws;            ws += (size_t)OVF_CAP * sizeof(int4);
  float* Z      = (float*)ws;           ws += (size_t)n * 2 * sizeof(float);
  float* Ha     = (float*)ws;           ws += (size_t)n * 2 * sizeof(float);
  float* Hb     = (float*)ws;           ws += (size_t)n * 2 * sizeof(float);
  unsigned short* W1F = (unsigned short*)ws;  ws += 2 * 16384 * sizeof(unsigned short);
  int*   rowoff = (int*)ws;             ws += (size_t)nbuck * RPB * sizeof(int);
  int*   gcnt   = (int*)ws;             ws += (size_t)nbuck * sizeof(int);
  int*   ovfN   = (int*)ws;             ws += 4 * sizeof(int);

  hipMemsetAsync(gcnt, 0, (size_t)nbuck * sizeof(int), stream);
  hipMemsetAsync(ovfN, 0, sizeof(int), stream);

  const int grid_b = (e + CHUNK - 1) / CHUNK;   // 256
  bucket_build2<<<grid_b, 512, 0, stream>>>(erows, ecols, evals, gcnt,
                                            binned, ovf, ovfN, e, nbuck);
  bucket_sort<<<nbuck, 512, 0, stream>>>(gcnt, binned, rowoff, nbuck);

  w1_frag<<<64, 256, 0, stream>>>(W1, W1F);
  mlp_mfma<<<(n + 63) / 64, 256, 0, stream>>>(x, W1F, b1, W2, b2, Z, n);

  const float cB = 1.f - ALPHA;
  const int grid_g = (4 * n + 255) / 256;
  const float* hin = Z;
  for (int t = 0; t < K_ITERS; ++t) {
    float* hout = (t == K_ITERS - 1) ? out : ((t & 1) ? Hb : Ha);
    sorted_gather<<<grid_g, 256, 0, stream>>>(rowoff, gcnt, binned, Z, hin, hout,
                                              ovf, ovfN, cB, n);
    hin = hout;
  }
}

// Round 12
// 310.730 us; speedup vs baseline: 1.5273x; 1.5273x over previous
//
#include <hip/hip_runtime.h>

#define IN_DIM 256
#define HID 64
#define K_ITERS 10
#define ALPHA 0.1f

constexpr int RPB      = 128;   // rows per bucket (bucket = row >> 7)
constexpr int BCAP     = 4992;  // slots per bucket; counts ~Poisson(4096)
constexpr int OVF_CAP  = 8192;
constexpr int MAXBUCK  = 800;   // nbuck = 782 here
constexpr int CHUNK    = 12544; // edges per build block

typedef __attribute__((ext_vector_type(8))) short short8v;
typedef __attribute__((ext_vector_type(4))) float float4v;

__device__ __forceinline__ unsigned short f32_bf16(float f) {
  unsigned u = __float_as_uint(f);
  u += 0x7FFFu + ((u >> 16) & 1u);
  return (unsigned short)(u >> 16);
}
__device__ __forceinline__ float bf16_f32(unsigned short h) {
  return __uint_as_float((unsigned)h << 16);
}

// ---------------- W1 -> fragment-ordered bf16 hi/lo planes ----------------
__global__ __launch_bounds__(256) void w1_frag(
    const float* __restrict__ W1, unsigned short* __restrict__ W1F)
{
  int idx = blockIdx.x * 256 + threadIdx.x;   // 16384
  int i  = idx & 7;
  int ln = (idx >> 3) & 63;
  int ht = (idx >> 9) & 3;
  int ks = idx >> 11;
  int hid = ht * 16 + (ln & 15);
  int k   = ks * 32 + (ln >> 4) * 8 + i;
  float v = W1[hid * IN_DIM + k];
  unsigned short hi = f32_bf16(v);
  unsigned short lo = f32_bf16(v - bf16_f32(hi));
  W1F[idx]         = hi;
  W1F[16384 + idx] = lo;
}

// ---------------- MLP via split-bf16 MFMA (proven round 8) ----------------
__global__ __launch_bounds__(256) void mlp_mfma(
    const float* __restrict__ x, const unsigned short* __restrict__ W1F,
    const float* __restrict__ b1, const float* __restrict__ W2,
    const float* __restrict__ b2, float* __restrict__ Z, int n)
{
  const int tid  = threadIdx.x;
  const int w    = tid >> 6;
  const int lane = tid & 63;
  const int m    = lane & 15;
  const int kg   = lane >> 4;
  const int node = blockIdx.x * 64 + w * 16 + m;
  const bool valid = node < n;
  const float* xrow = x + (size_t)(valid ? node : 0) * IN_DIM;

  const short8v* Bhi = reinterpret_cast<const short8v*>(W1F);
  const short8v* Blo = Bhi + 2048;

  float4v acc[4];
  #pragma unroll
  for (int ht = 0; ht < 4; ++ht) acc[ht] = (float4v){0.f, 0.f, 0.f, 0.f};

  #pragma unroll
  for (int ks = 0; ks < 8; ++ks) {
    const int kb = ks * 32 + kg * 8;
    float4 a0 = *reinterpret_cast<const float4*>(xrow + kb);
    float4 a1 = *reinterpret_cast<const float4*>(xrow + kb + 4);
    float xv[8] = {a0.x, a0.y, a0.z, a0.w, a1.x, a1.y, a1.z, a1.w};
    short8v ahi, alo;
    #pragma unroll
    for (int i = 0; i < 8; ++i) {
      unsigned short h = f32_bf16(xv[i]);
      ahi[i] = (short)h;
      alo[i] = (short)f32_bf16(xv[i] - bf16_f32(h));
    }
    #pragma unroll
    for (int ht = 0; ht < 4; ++ht) {
      int bidx = (ks * 4 + ht) * 64 + lane;
      short8v bh = Bhi[bidx];
      short8v bl = Blo[bidx];
      acc[ht] = __builtin_amdgcn_mfma_f32_16x16x32_bf16(ahi, bh, acc[ht], 0, 0, 0);
      acc[ht] = __builtin_amdgcn_mfma_f32_16x16x32_bf16(alo, bh, acc[ht], 0, 0, 0);
      acc[ht] = __builtin_amdgcn_mfma_f32_16x16x32_bf16(ahi, bl, acc[ht], 0, 0, 0);
    }
  }

  float p0[4] = {0.f, 0.f, 0.f, 0.f}, p1[4] = {0.f, 0.f, 0.f, 0.f};
  #pragma unroll
  for (int ht = 0; ht < 4; ++ht) {
    int hid = ht * 16 + m;
    float w0 = W2[hid], w1v = W2[HID + hid], bb = b1[hid];
    #pragma unroll
    for (int j = 0; j < 4; ++j) {
      float h = fmaxf(acc[ht][j] + bb, 0.f);
      p0[j] = fmaf(h, w0, p0[j]);
      p1[j] = fmaf(h, w1v, p1[j]);
    }
  }
  #pragma unroll
  for (int j = 0; j < 4; ++j) {
    #pragma unroll
    for (int s = 1; s < 16; s <<= 1) {
      p0[j] += __shfl_xor(p0[j], s);
      p1[j] += __shfl_xor(p1[j], s);
    }
  }
  if (m == 0) {
    #pragma unroll
    for (int j = 0; j < 4; ++j) {
      int nd = blockIdx.x * 64 + w * 16 + kg * 4 + j;
      if (nd < n) {
        Z[(size_t)nd * 2 + 0] = p0[j] + b2[0];
        Z[(size_t)nd * 2 + 1] = p1[j] + b2[1];
      }
    }
  }
}

// ---------------- Bucket build v3: LDS-reordered, coalesced write-out ------
__global__ __launch_bounds__(512) void bucket_build2(
    const int* __restrict__ rows, const int* __restrict__ cols,
    const float* __restrict__ vals, int* __restrict__ gcnt,
    int2* __restrict__ binned, int4* __restrict__ ovf, int* __restrict__ ovfN,
    int e, int nbuck)
{
  __shared__ int2 buf[CHUNK];                 // 100.4 KB
  __shared__ unsigned short sb[CHUNK];        // 25.1 KB
  __shared__ int h1[MAXBUCK];
  __shared__ int scn[2][MAXBUCK];
  __shared__ int lofs[MAXBUCK];
  __shared__ int cur[MAXBUCK];
  __shared__ int gbase[MAXBUCK];

  const int tid = threadIdx.x;
  const int beg = blockIdx.x * CHUNK;
  const int end = min(beg + CHUNK, e);
  const int cnt = end - beg;

  for (int b = tid; b < nbuck; b += 512) h1[b] = 0;
  __syncthreads();

  for (int i = beg + tid; i < end; i += 512)
    atomicAdd(&h1[rows[i] >> 7], 1);
  __syncthreads();

  int p = 0;
  for (int b = tid; b < nbuck; b += 512) scn[0][b] = h1[b];
  __syncthreads();
  for (int off = 1; off < nbuck; off <<= 1) {
    for (int b = tid; b < nbuck; b += 512)
      scn[p ^ 1][b] = (b >= off) ? scn[p][b] + scn[p][b - off] : scn[p][b];
    __syncthreads();
    p ^= 1;
  }
  for (int b = tid; b < nbuck; b += 512) {
    int ex = (b == 0) ? 0 : scn[p][b - 1];
    lofs[b] = ex;
    cur[b]  = ex;
  }
  __syncthreads();

  for (int i = beg + tid; i < end; i += 512) {
    int r = rows[i];
    int b = r >> 7;
    int pos = atomicAdd(&cur[b], 1);
    buf[pos] = make_int2(((r & 127) << 17) | cols[i], __float_as_int(vals[i]));
    sb[pos]  = (unsigned short)b;
  }
  for (int b = tid; b < nbuck; b += 512)
    gbase[b] = h1[b] ? atomicAdd(&gcnt[b], h1[b]) : 0;
  __syncthreads();

  for (int i = tid; i < cnt; i += 512) {
    int b = sb[i];
    int pos = gbase[b] + (i - lofs[b]);
    int2 ed = buf[i];
    if (pos < BCAP) {
      binned[(size_t)b * BCAP + pos] = ed;
    } else {
      int k = atomicAdd(ovfN, 1);
      if (k < OVF_CAP) ovf[k] = make_int4(b, ed.x, ed.y, 0);
    }
  }
}

// ---------------- Row-sort each bucket + bucket-local CSR offsets ----------
__global__ __launch_bounds__(512) void bucket_sort(
    const int* __restrict__ gcnt, int2* __restrict__ binned,
    int* __restrict__ rowoff, int nbuck)
{
  __shared__ int2 buf[BCAP];
  __shared__ int hist[RPB];
  __shared__ int offs[RPB];
  __shared__ int cur[RPB];
  const int b = blockIdx.x, tid = threadIdx.x;
  const int cnt = min(gcnt[b], BCAP);
  int2* gp = binned + (size_t)b * BCAP;

  if (tid < RPB) hist[tid] = 0;
  __syncthreads();
  for (int i = tid; i < cnt; i += 512) {
    int2 e = gp[i];
    buf[i] = e;
    atomicAdd(&hist[e.x >> 17], 1);
  }
  __syncthreads();
  if (tid == 0) {
    int run = 0;
    for (int r = 0; r < RPB; ++r) { offs[r] = run; cur[r] = run; run += hist[r]; }
  }
  __syncthreads();
  if (tid < RPB) rowoff[b * RPB + tid] = offs[tid];
  for (int i = tid; i < cnt; i += 512) {
    int2 e = buf[i];
    int pos = atomicAdd(&cur[e.x >> 17], 1);
    gp[pos] = e;
  }
}

// ---------------- APPNP step: row-segment gather, paired int4 edges --------
// Plain (cached) loads — binned (~3.2 MB/XCD) and H (0.8 MB) both stay
// L2-resident across iterations (round-11 lesson: nt loads evict the hot
// stream and regress 1.7x). int4 = 2 edges per load instruction cuts the
// VMEM-issue count 25%.
__global__ __launch_bounds__(256) void sorted_gather(
    const int* __restrict__ rowoff, const int* __restrict__ gcnt,
    const int2* __restrict__ binned, const float* __restrict__ Z,
    const float* __restrict__ Hin, float* __restrict__ Hout,
    const int4* __restrict__ ovf, const int* __restrict__ ovfN,
    float cB, int n)
{
  int g = blockIdx.x * 256 + threadIdx.x;
  int r = g >> 2, l = g & 3;
  if (r >= n) return;
  int b = r >> 7, rl = r & 127;
  int cntraw = gcnt[b];
  int cnt = min(cntraw, BCAP);
  int beg = rowoff[b * RPB + rl];
  int end = (rl == RPB - 1) ? cnt : rowoff[b * RPB + rl + 1];
  const int2* bp = binned + (size_t)b * BCAP;   // 16B-aligned (BCAP*8 % 16 == 0)
  float sx = 0.f, sy = 0.f;

  const int astart = (beg + 1) & ~1;            // first even index >= beg
  // head edge (beg odd) -> lane 0; tail edge ((end-astart) odd) -> lane 1
  if (l == 0 && beg < astart && beg < end) {
    int2 p0 = bp[beg];
    float v = __int_as_float(p0.y);
    float2 h = *reinterpret_cast<const float2*>(&Hin[(size_t)(p0.x & 0x1FFFF) * 2]);
    sx = fmaf(v, h.x, sx); sy = fmaf(v, h.y, sy);
  }
  int npair = (end > astart) ? ((end - astart) >> 1) : 0;
  if (l == 1 && end > astart && ((end - astart) & 1)) {
    int2 p0 = bp[end - 1];
    float v = __int_as_float(p0.y);
    float2 h = *reinterpret_cast<const float2*>(&Hin[(size_t)(p0.x & 0x1FFFF) * 2]);
    sx = fmaf(v, h.x, sx); sy = fmaf(v, h.y, sy);
  }
  const int4* bp4 = reinterpret_cast<const int4*>(bp) + (astart >> 1);
  for (int k = l; k < npair; k += 4) {
    int4 p = bp4[k];                            // edges (p.x,p.y) and (p.z,p.w)
    float vA = __int_as_float(p.y), vB = __int_as_float(p.w);
    float2 hA = *reinterpret_cast<const float2*>(&Hin[(size_t)(p.x & 0x1FFFF) * 2]);
    float2 hB = *reinterpret_cast<const float2*>(&Hin[(size_t)(p.z & 0x1FFFF) * 2]);
    sx = fmaf(vA, hA.x, fmaf(vB, hB.x, sx));
    sy = fmaf(vA, hA.y, fmaf(vB, hB.y, sy));
  }

  if (cntraw > BCAP) {                          // statistically never
    int mo = min(*ovfN, OVF_CAP);
    for (int j = l; j < mo; j += 4) {
      int4 o = ovf[j];
      if (o.x == b && (o.y >> 17) == rl) {
        int col = o.y & 0x1FFFF;
        float v = __int_as_float(o.z);
        float2 h = *reinterpret_cast<const float2*>(&Hin[(size_t)col * 2]);
        sx += v * h.x; sy += v * h.y;
      }
    }
  }
  sx += __shfl_xor(sx, 1); sy += __shfl_xor(sy, 1);
  sx += __shfl_xor(sx, 2); sy += __shfl_xor(sy, 2);
  if (l == 0) {
    float2 z = *reinterpret_cast<const float2*>(&Z[(size_t)r * 2]);
    reinterpret_cast<float2*>(Hout)[r] =
        make_float2(ALPHA * z.x + cB * sx, ALPHA * z.y + cB * sy);
  }
}

extern "C" void kernel_launch(void* const* d_in, const int* in_sizes, int n_in,
                              void* d_out, int out_size, void* d_ws, size_t ws_size,
                              hipStream_t stream) {
  const float* x     = (const float*)d_in[0];
  const float* W1    = (const float*)d_in[1];
  const float* b1    = (const float*)d_in[2];
  const float* W2    = (const float*)d_in[3];
  const float* b2    = (const float*)d_in[4];
  const int*   erows = (const int*)d_in[5];
  const int*   ecols = (const int*)d_in[6];
  const float* evals = (const float*)d_in[7];
  float* out = (float*)d_out;

  const int n = in_sizes[0] / IN_DIM;     // 100000
  const int e = in_sizes[5];              // 3200000
  const int nbuck = (n + RPB - 1) / RPB;  // 782

  char* ws = (char*)d_ws;
  int2*  binned = (int2*)ws;            ws += (size_t)nbuck * BCAP * sizeof(int2);
  int4*  ovf    = (int4*)ws;            ws += (size_t)OVF_CAP * sizeof(int4);
  float* Z      = (float*)ws;           ws += (size_t)n * 2 * sizeof(float);
  float* Ha     = (float*)ws;           ws += (size_t)n * 2 * sizeof(float);
  float* Hb     = (float*)ws;           ws += (size_t)n * 2 * sizeof(float);
  unsigned short* W1F = (unsigned short*)ws;  ws += 2 * 16384 * sizeof(unsigned short);
  int*   rowoff = (int*)ws;             ws += (size_t)nbuck * RPB * sizeof(int);
  int*   gcnt   = (int*)ws;             ws += (size_t)nbuck * sizeof(int);
  int*   ovfN   = (int*)ws;             ws += 4 * sizeof(int);

  hipMemsetAsync(gcnt, 0, (size_t)nbuck * sizeof(int), stream);
  hipMemsetAsync(ovfN, 0, sizeof(int), stream);

  const int grid_b = (e + CHUNK - 1) / CHUNK;   // 256
  bucket_build2<<<grid_b, 512, 0, stream>>>(erows, ecols, evals, gcnt,
                                            binned, ovf, ovfN, e, nbuck);
  bucket_sort<<<nbuck, 512, 0, stream>>>(gcnt, binned, rowoff, nbuck);

  w1_frag<<<64, 256, 0, stream>>>(W1, W1F);
  mlp_mfma<<<(n + 63) / 64, 256, 0, stream>>>(x, W1F, b1, W2, b2, Z, n);

  const float cB = 1.f - ALPHA;
  const int grid_g = (4 * n + 255) / 256;
  const float* hin = Z;
  for (int t = 0; t < K_ITERS; ++t) {
    float* hout = (t == K_ITERS - 1) ? out : ((t & 1) ? Hb : Ha);
    sorted_gather<<<grid_g, 256, 0, stream>>>(rowoff, gcnt, binned, Z, hin, hout,
                                              ovf, ovfN, cB, n);
    hin = hout;
  }
}

// Round 13
// 305.046 us; speedup vs baseline: 1.5557x; 1.0186x over previous
//
#include <hip/hip_runtime.h>

#define IN_DIM 256
#define HID 64
#define K_ITERS 10
#define ALPHA 0.1f

constexpr int RPB      = 128;   // rows per bucket (bucket = row >> 7)
constexpr int BCAP     = 4992;  // slots per bucket; counts ~Poisson(4096)
constexpr int OVF_CAP  = 8192;
constexpr int MAXBUCK  = 800;   // nbuck = 782 here
constexpr int CHUNK    = 12544; // edges per build block

typedef __attribute__((ext_vector_type(8))) short short8v;
typedef __attribute__((ext_vector_type(4))) float float4v;

__device__ __forceinline__ unsigned short f32_bf16(float f) {
  unsigned u = __float_as_uint(f);
  u += 0x7FFFu + ((u >> 16) & 1u);
  return (unsigned short)(u >> 16);
}
__device__ __forceinline__ float bf16_f32(unsigned short h) {
  return __uint_as_float((unsigned)h << 16);
}

// ---------------- W1 -> fragment-ordered bf16 hi/lo planes ----------------
__global__ __launch_bounds__(256) void w1_frag(
    const float* __restrict__ W1, unsigned short* __restrict__ W1F)
{
  int idx = blockIdx.x * 256 + threadIdx.x;   // 16384
  int i  = idx & 7;
  int ln = (idx >> 3) & 63;
  int ht = (idx >> 9) & 3;
  int ks = idx >> 11;
  int hid = ht * 16 + (ln & 15);
  int k   = ks * 32 + (ln >> 4) * 8 + i;
  float v = W1[hid * IN_DIM + k];
  unsigned short hi = f32_bf16(v);
  unsigned short lo = f32_bf16(v - bf16_f32(hi));
  W1F[idx]         = hi;
  W1F[16384 + idx] = lo;
}

// ---------------- MLP via split-bf16 MFMA (proven round 8) ----------------
__global__ __launch_bounds__(256) void mlp_mfma(
    const float* __restrict__ x, const unsigned short* __restrict__ W1F,
    const float* __restrict__ b1, const float* __restrict__ W2,
    const float* __restrict__ b2, float* __restrict__ Z, int n)
{
  const int tid  = threadIdx.x;
  const int w    = tid >> 6;
  const int lane = tid & 63;
  const int m    = lane & 15;
  const int kg   = lane >> 4;
  const int node = blockIdx.x * 64 + w * 16 + m;
  const bool valid = node < n;
  const float* xrow = x + (size_t)(valid ? node : 0) * IN_DIM;

  const short8v* Bhi = reinterpret_cast<const short8v*>(W1F);
  const short8v* Blo = Bhi + 2048;

  float4v acc[4];
  #pragma unroll
  for (int ht = 0; ht < 4; ++ht) acc[ht] = (float4v){0.f, 0.f, 0.f, 0.f};

  #pragma unroll
  for (int ks = 0; ks < 8; ++ks) {
    const int kb = ks * 32 + kg * 8;
    float4 a0 = *reinterpret_cast<const float4*>(xrow + kb);
    float4 a1 = *reinterpret_cast<const float4*>(xrow + kb + 4);
    float xv[8] = {a0.x, a0.y, a0.z, a0.w, a1.x, a1.y, a1.z, a1.w};
    short8v ahi, alo;
    #pragma unroll
    for (int i = 0; i < 8; ++i) {
      unsigned short h = f32_bf16(xv[i]);
      ahi[i] = (short)h;
      alo[i] = (short)f32_bf16(xv[i] - bf16_f32(h));
    }
    #pragma unroll
    for (int ht = 0; ht < 4; ++ht) {
      int bidx = (ks * 4 + ht) * 64 + lane;
      short8v bh = Bhi[bidx];
      short8v bl = Blo[bidx];
      acc[ht] = __builtin_amdgcn_mfma_f32_16x16x32_bf16(ahi, bh, acc[ht], 0, 0, 0);
      acc[ht] = __builtin_amdgcn_mfma_f32_16x16x32_bf16(alo, bh, acc[ht], 0, 0, 0);
      acc[ht] = __builtin_amdgcn_mfma_f32_16x16x32_bf16(ahi, bl, acc[ht], 0, 0, 0);
    }
  }

  float p0[4] = {0.f, 0.f, 0.f, 0.f}, p1[4] = {0.f, 0.f, 0.f, 0.f};
  #pragma unroll
  for (int ht = 0; ht < 4; ++ht) {
    int hid = ht * 16 + m;
    float w0 = W2[hid], w1v = W2[HID + hid], bb = b1[hid];
    #pragma unroll
    for (int j = 0; j < 4; ++j) {
      float h = fmaxf(acc[ht][j] + bb, 0.f);
      p0[j] = fmaf(h, w0, p0[j]);
      p1[j] = fmaf(h, w1v, p1[j]);
    }
  }
  #pragma unroll
  for (int j = 0; j < 4; ++j) {
    #pragma unroll
    for (int s = 1; s < 16; s <<= 1) {
      p0[j] += __shfl_xor(p0[j], s);
      p1[j] += __shfl_xor(p1[j], s);
    }
  }
  if (m == 0) {
    #pragma unroll
    for (int j = 0; j < 4; ++j) {
      int nd = blockIdx.x * 64 + w * 16 + kg * 4 + j;
      if (nd < n) {
        Z[(size_t)nd * 2 + 0] = p0[j] + b2[0];
        Z[(size_t)nd * 2 + 1] = p1[j] + b2[1];
      }
    }
  }
}

// ---------------- Bucket build v3: LDS-reordered, coalesced write-out ------
__global__ __launch_bounds__(512) void bucket_build2(
    const int* __restrict__ rows, const int* __restrict__ cols,
    const float* __restrict__ vals, int* __restrict__ gcnt,
    int2* __restrict__ binned, int4* __restrict__ ovf, int* __restrict__ ovfN,
    int e, int nbuck)
{
  __shared__ int2 buf[CHUNK];                 // 100.4 KB
  __shared__ unsigned short sb[CHUNK];        // 25.1 KB
  __shared__ int h1[MAXBUCK];
  __shared__ int scn[2][MAXBUCK];
  __shared__ int lofs[MAXBUCK];
  __shared__ int cur[MAXBUCK];
  __shared__ int gbase[MAXBUCK];

  const int tid = threadIdx.x;
  const int beg = blockIdx.x * CHUNK;
  const int end = min(beg + CHUNK, e);
  const int cnt = end - beg;

  for (int b = tid; b < nbuck; b += 512) h1[b] = 0;
  __syncthreads();

  for (int i = beg + tid; i < end; i += 512)
    atomicAdd(&h1[rows[i] >> 7], 1);
  __syncthreads();

  int p = 0;
  for (int b = tid; b < nbuck; b += 512) scn[0][b] = h1[b];
  __syncthreads();
  for (int off = 1; off < nbuck; off <<= 1) {
    for (int b = tid; b < nbuck; b += 512)
      scn[p ^ 1][b] = (b >= off) ? scn[p][b] + scn[p][b - off] : scn[p][b];
    __syncthreads();
    p ^= 1;
  }
  for (int b = tid; b < nbuck; b += 512) {
    int ex = (b == 0) ? 0 : scn[p][b - 1];
    lofs[b] = ex;
    cur[b]  = ex;
  }
  __syncthreads();

  for (int i = beg + tid; i < end; i += 512) {
    int r = rows[i];
    int b = r >> 7;
    int pos = atomicAdd(&cur[b], 1);
    buf[pos] = make_int2(((r & 127) << 17) | cols[i], __float_as_int(vals[i]));
    sb[pos]  = (unsigned short)b;
  }
  for (int b = tid; b < nbuck; b += 512)
    gbase[b] = h1[b] ? atomicAdd(&gcnt[b], h1[b]) : 0;
  __syncthreads();

  for (int i = tid; i < cnt; i += 512) {
    int b = sb[i];
    int pos = gbase[b] + (i - lofs[b]);
    int2 ed = buf[i];
    if (pos < BCAP) {
      binned[(size_t)b * BCAP + pos] = ed;
    } else {
      int k = atomicAdd(ovfN, 1);
      if (k < OVF_CAP) ovf[k] = make_int4(b, ed.x, ed.y, 0);
    }
  }
}

// ---------------- Row-sort each bucket + bucket-local CSR offsets ----------
__global__ __launch_bounds__(512) void bucket_sort(
    const int* __restrict__ gcnt, int2* __restrict__ binned,
    int* __restrict__ rowoff, int nbuck)
{
  __shared__ int2 buf[BCAP];
  __shared__ int hist[RPB];
  __shared__ int offs[RPB];
  __shared__ int cur[RPB];
  const int b = blockIdx.x, tid = threadIdx.x;
  const int cnt = min(gcnt[b], BCAP);
  int2* gp = binned + (size_t)b * BCAP;

  if (tid < RPB) hist[tid] = 0;
  __syncthreads();
  for (int i = tid; i < cnt; i += 512) {
    int2 e = gp[i];
    buf[i] = e;
    atomicAdd(&hist[e.x >> 17], 1);
  }
  __syncthreads();
  if (tid == 0) {
    int run = 0;
    for (int r = 0; r < RPB; ++r) { offs[r] = run; cur[r] = run; run += hist[r]; }
  }
  __syncthreads();
  if (tid < RPB) rowoff[b * RPB + tid] = offs[tid];
  for (int i = tid; i < cnt; i += 512) {
    int2 e = buf[i];
    int pos = atomicAdd(&cur[e.x >> 17], 1);
    gp[pos] = e;
  }
}

// ---------------- APPNP step: row-segment gather, batched edge preload -----
// 8 predicated int4 preloads (static indices -> registers) put all edge loads
// in flight before the dependent H loads; covers deg<=64 fully (P(deg>64) ~
// 3e-7), global tail loop for the rest.
__global__ __launch_bounds__(256) void sorted_gather(
    const int* __restrict__ rowoff, const int* __restrict__ gcnt,
    const int2* __restrict__ binned, const float* __restrict__ Z,
    const float* __restrict__ Hin, float* __restrict__ Hout,
    const int4* __restrict__ ovf, const int* __restrict__ ovfN,
    float cB, int n)
{
  int g = blockIdx.x * 256 + threadIdx.x;
  int r = g >> 2, l = g & 3;
  if (r >= n) return;
  int b = r >> 7, rl = r & 127;
  int cntraw = gcnt[b];
  int cnt = min(cntraw, BCAP);
  int beg = rowoff[b * RPB + rl];
  int end = (rl == RPB - 1) ? cnt : rowoff[b * RPB + rl + 1];
  const int2* bp = binned + (size_t)b * BCAP;   // 16B-aligned
  float sx = 0.f, sy = 0.f;

  const int astart = (beg + 1) & ~1;
  if (l == 0 && beg < astart && beg < end) {
    int2 p0 = bp[beg];
    float v = __int_as_float(p0.y);
    float2 h = *reinterpret_cast<const float2*>(&Hin[(size_t)(p0.x & 0x1FFFF) * 2]);
    sx = fmaf(v, h.x, sx); sy = fmaf(v, h.y, sy);
  }
  int npair = (end > astart) ? ((end - astart) >> 1) : 0;
  if (l == 1 && end > astart && ((end - astart) & 1)) {
    int2 p0 = bp[end - 1];
    float v = __int_as_float(p0.y);
    float2 h = *reinterpret_cast<const float2*>(&Hin[(size_t)(p0.x & 0x1FFFF) * 2]);
    sx = fmaf(v, h.x, sx); sy = fmaf(v, h.y, sy);
  }
  const int4* bp4 = reinterpret_cast<const int4*>(bp) + (astart >> 1);

  // batched preload: all edge loads issue before any H load
  int4 eb[8];
  #pragma unroll
  for (int c = 0; c < 8; ++c) {
    int k = l + 4 * c;
    if (k < npair) eb[c] = bp4[k];
  }
  #pragma unroll
  for (int c = 0; c < 8; ++c) {
    int k = l + 4 * c;
    if (k < npair) {
      int4 p = eb[c];
      float vA = __int_as_float(p.y), vB = __int_as_float(p.w);
      float2 hA = *reinterpret_cast<const float2*>(&Hin[(size_t)(p.x & 0x1FFFF) * 2]);
      float2 hB = *reinterpret_cast<const float2*>(&Hin[(size_t)(p.z & 0x1FFFF) * 2]);
      sx = fmaf(vA, hA.x, fmaf(vB, hB.x, sx));
      sy = fmaf(vA, hA.y, fmaf(vB, hB.y, sy));
    }
  }
  for (int k = l + 32; k < npair; k += 4) {     // deg > 64: ~never
    int4 p = bp4[k];
    float vA = __int_as_float(p.y), vB = __int_as_float(p.w);
    float2 hA = *reinterpret_cast<const float2*>(&Hin[(size_t)(p.x & 0x1FFFF) * 2]);
    float2 hB = *reinterpret_cast<const float2*>(&Hin[(size_t)(p.z & 0x1FFFF) * 2]);
    sx = fmaf(vA, hA.x, fmaf(vB, hB.x, sx));
    sy = fmaf(vA, hA.y, fmaf(vB, hB.y, sy));
  }

  if (cntraw > BCAP) {                          // statistically never
    int mo = min(*ovfN, OVF_CAP);
    for (int j = l; j < mo; j += 4) {
      int4 o = ovf[j];
      if (o.x == b && (o.y >> 17) == rl) {
        int col = o.y & 0x1FFFF;
        float v = __int_as_float(o.z);
        float2 h = *reinterpret_cast<const float2*>(&Hin[(size_t)col * 2]);
        sx += v * h.x; sy += v * h.y;
      }
    }
  }
  sx += __shfl_xor(sx, 1); sy += __shfl_xor(sy, 1);
  sx += __shfl_xor(sx, 2); sy += __shfl_xor(sy, 2);
  if (l == 0) {
    float2 z = *reinterpret_cast<const float2*>(&Z[(size_t)r * 2]);
    reinterpret_cast<float2*>(Hout)[r] =
        make_float2(ALPHA * z.x + cB * sx, ALPHA * z.y + cB * sy);
  }
}

extern "C" void kernel_launch(void* const* d_in, const int* in_sizes, int n_in,
                              void* d_out, int out_size, void* d_ws, size_t ws_size,
                              hipStream_t stream) {
  const float* x     = (const float*)d_in[0];
  const float* W1    = (const float*)d_in[1];
  const float* b1    = (const float*)d_in[2];
  const float* W2    = (const float*)d_in[3];
  const float* b2    = (const float*)d_in[4];
  const int*   erows = (const int*)d_in[5];
  const int*   ecols = (const int*)d_in[6];
  const float* evals = (const float*)d_in[7];
  float* out = (float*)d_out;

  const int n = in_sizes[0] / IN_DIM;     // 100000
  const int e = in_sizes[5];              // 3200000
  const int nbuck = (n + RPB - 1) / RPB;  // 782

  char* ws = (char*)d_ws;
  int2*  binned = (int2*)ws;            ws += (size_t)nbuck * BCAP * sizeof(int2);
  int4*  ovf    = (int4*)ws;            ws += (size_t)OVF_CAP * sizeof(int4);
  float* Z      = (float*)ws;           ws += (size_t)n * 2 * sizeof(float);
  float* Ha     = (float*)ws;           ws += (size_t)n * 2 * sizeof(float);
  float* Hb     = (float*)ws;           ws += (size_t)n * 2 * sizeof(float);
  unsigned short* W1F = (unsigned short*)ws;  ws += 2 * 16384 * sizeof(unsigned short);
  int*   rowoff = (int*)ws;             ws += (size_t)nbuck * RPB * sizeof(int);
  int*   gcnt   = (int*)ws;             ws += (size_t)nbuck * sizeof(int);
  int*   ovfN   = (int*)ws;             ws += 4 * sizeof(int);

  hipMemsetAsync(gcnt, 0, (size_t)nbuck * sizeof(int), stream);
  hipMemsetAsync(ovfN, 0, sizeof(int), stream);

  const int grid_b = (e + CHUNK - 1) / CHUNK;   // 256
  bucket_build2<<<grid_b, 512, 0, stream>>>(erows, ecols, evals, gcnt,
                                            binned, ovf, ovfN, e, nbuck);
  bucket_sort<<<nbuck, 512, 0, stream>>>(gcnt, binned, rowoff, nbuck);

  w1_frag<<<64, 256, 0, stream>>>(W1, W1F);
  mlp_mfma<<<(n + 63) / 64, 256, 0, stream>>>(x, W1F, b1, W2, b2, Z, n);

  const float cB = 1.f - ALPHA;
  const int grid_g = (4 * n + 255) / 256;
  const float* hin = Z;
  for (int t = 0; t < K_ITERS; ++t) {
    float* hout = (t == K_ITERS - 1) ? out : ((t & 1) ? Hb : Ha);
    sorted_gather<<<grid_g, 256, 0, stream>>>(rowoff, gcnt, binned, Z, hin, hout,
                                              ovf, ovfN, cB, n);
    hin = hout;
  }
}

// Round 14
// 296.470 us; speedup vs baseline: 1.6007x; 1.0289x over previous
//
#include <hip/hip_runtime.h>

#define IN_DIM 256
#define HID 64
#define K_ITERS 10
#define ALPHA 0.1f

constexpr int RPB      = 128;   // rows per bucket (bucket = row >> 7)
constexpr int BCAP     = 4992;  // slots per bucket; counts ~Poisson(4096)
constexpr int OVF_CAP  = 8192;
constexpr int MAXBUCK  = 784;   // nbuck = 782 here
constexpr int CHUNK    = 6272;  // edges per build block -> 78.4 KB LDS, 2 blocks/CU

typedef __attribute__((ext_vector_type(8))) short short8v;
typedef __attribute__((ext_vector_type(4))) float float4v;

__device__ __forceinline__ unsigned short f32_bf16(float f) {
  unsigned u = __float_as_uint(f);
  u += 0x7FFFu + ((u >> 16) & 1u);
  return (unsigned short)(u >> 16);
}
__device__ __forceinline__ float bf16_f32(unsigned short h) {
  return __uint_as_float((unsigned)h << 16);
}

// ---------------- W1 -> fragment bf16 hi/lo planes + zero gcnt/ovfN --------
__global__ __launch_bounds__(256) void w1_frag(
    const float* __restrict__ W1, unsigned short* __restrict__ W1F,
    int* __restrict__ gcnt, int* __restrict__ ovfN, int nbuck)
{
  int idx = blockIdx.x * 256 + threadIdx.x;   // 16384
  if (blockIdx.x == 0) {                      // fused zeroing (pre-build2)
    for (int b = threadIdx.x; b < nbuck; b += 256) gcnt[b] = 0;
    if (threadIdx.x == 0) *ovfN = 0;
  }
  int i  = idx & 7;
  int ln = (idx >> 3) & 63;
  int ht = (idx >> 9) & 3;
  int ks = idx >> 11;
  int hid = ht * 16 + (ln & 15);
  int k   = ks * 32 + (ln >> 4) * 8 + i;
  float v = W1[hid * IN_DIM + k];
  unsigned short hi = f32_bf16(v);
  unsigned short lo = f32_bf16(v - bf16_f32(hi));
  W1F[idx]         = hi;
  W1F[16384 + idx] = lo;
}

// ---------------- MLP via split-bf16 MFMA (proven round 8) ----------------
__global__ __launch_bounds__(256) void mlp_mfma(
    const float* __restrict__ x, const unsigned short* __restrict__ W1F,
    const float* __restrict__ b1, const float* __restrict__ W2,
    const float* __restrict__ b2, float* __restrict__ Z, int n)
{
  const int tid  = threadIdx.x;
  const int w    = tid >> 6;
  const int lane = tid & 63;
  const int m    = lane & 15;
  const int kg   = lane >> 4;
  const int node = blockIdx.x * 64 + w * 16 + m;
  const bool valid = node < n;
  const float* xrow = x + (size_t)(valid ? node : 0) * IN_DIM;

  const short8v* Bhi = reinterpret_cast<const short8v*>(W1F);
  const short8v* Blo = Bhi + 2048;

  float4v acc[4];
  #pragma unroll
  for (int ht = 0; ht < 4; ++ht) acc[ht] = (float4v){0.f, 0.f, 0.f, 0.f};

  #pragma unroll
  for (int ks = 0; ks < 8; ++ks) {
    const int kb = ks * 32 + kg * 8;
    float4 a0 = *reinterpret_cast<const float4*>(xrow + kb);
    float4 a1 = *reinterpret_cast<const float4*>(xrow + kb + 4);
    float xv[8] = {a0.x, a0.y, a0.z, a0.w, a1.x, a1.y, a1.z, a1.w};
    short8v ahi, alo;
    #pragma unroll
    for (int i = 0; i < 8; ++i) {
      unsigned short h = f32_bf16(xv[i]);
      ahi[i] = (short)h;
      alo[i] = (short)f32_bf16(xv[i] - bf16_f32(h));
    }
    #pragma unroll
    for (int ht = 0; ht < 4; ++ht) {
      int bidx = (ks * 4 + ht) * 64 + lane;
      short8v bh = Bhi[bidx];
      short8v bl = Blo[bidx];
      acc[ht] = __builtin_amdgcn_mfma_f32_16x16x32_bf16(ahi, bh, acc[ht], 0, 0, 0);
      acc[ht] = __builtin_amdgcn_mfma_f32_16x16x32_bf16(alo, bh, acc[ht], 0, 0, 0);
      acc[ht] = __builtin_amdgcn_mfma_f32_16x16x32_bf16(ahi, bl, acc[ht], 0, 0, 0);
    }
  }

  float p0[4] = {0.f, 0.f, 0.f, 0.f}, p1[4] = {0.f, 0.f, 0.f, 0.f};
  #pragma unroll
  for (int ht = 0; ht < 4; ++ht) {
    int hid = ht * 16 + m;
    float w0 = W2[hid], w1v = W2[HID + hid], bb = b1[hid];
    #pragma unroll
    for (int j = 0; j < 4; ++j) {
      float h = fmaxf(acc[ht][j] + bb, 0.f);
      p0[j] = fmaf(h, w0, p0[j]);
      p1[j] = fmaf(h, w1v, p1[j]);
    }
  }
  #pragma unroll
  for (int j = 0; j < 4; ++j) {
    #pragma unroll
    for (int s = 1; s < 16; s <<= 1) {
      p0[j] += __shfl_xor(p0[j], s);
      p1[j] += __shfl_xor(p1[j], s);
    }
  }
  if (m == 0) {
    #pragma unroll
    for (int j = 0; j < 4; ++j) {
      int nd = blockIdx.x * 64 + w * 16 + kg * 4 + j;
      if (nd < n) {
        Z[(size_t)nd * 2 + 0] = p0[j] + b2[0];
        Z[(size_t)nd * 2 + 1] = p1[j] + b2[1];
      }
    }
  }
}

// ---------------- Bucket build v4: LDS-reordered, 2 blocks/CU --------------
__global__ __launch_bounds__(512) void bucket_build2(
    const int* __restrict__ rows, const int* __restrict__ cols,
    const float* __restrict__ vals, int* __restrict__ gcnt,
    int2* __restrict__ binned, int4* __restrict__ ovf, int* __restrict__ ovfN,
    int e, int nbuck)
{
  __shared__ int2 buf[CHUNK];                 // 50.2 KB
  __shared__ unsigned short sb[CHUNK];        // 12.5 KB
  __shared__ int h1[MAXBUCK];                 // 5 x 3.1 KB
  __shared__ int scn[MAXBUCK];
  __shared__ int lofs[MAXBUCK];
  __shared__ int cur[MAXBUCK];
  __shared__ int gbase[MAXBUCK];

  const int tid = threadIdx.x;
  const int beg = blockIdx.x * CHUNK;
  const int end = min(beg + CHUNK, e);
  const int cnt = end - beg;

  for (int b = tid; b < nbuck; b += 512) h1[b] = 0;
  __syncthreads();

  // phase 1: histogram
  for (int i = beg + tid; i < end; i += 512)
    atomicAdd(&h1[rows[i] >> 7], 1);
  __syncthreads();

  // inclusive Hillis-Steele scan, single buffer (register temps + 2 syncs)
  const int b0 = tid, b1 = tid + 512;
  if (b0 < nbuck) scn[b0] = h1[b0];
  if (b1 < nbuck) scn[b1] = h1[b1];
  __syncthreads();
  for (int off = 1; off < nbuck; off <<= 1) {
    int t0 = 0, t1 = 0;
    if (b0 < nbuck) t0 = scn[b0] + ((b0 >= off) ? scn[b0 - off] : 0);
    if (b1 < nbuck) t1 = scn[b1] + ((b1 >= off) ? scn[b1 - off] : 0);
    __syncthreads();
    if (b0 < nbuck) scn[b0] = t0;
    if (b1 < nbuck) scn[b1] = t1;
    __syncthreads();
  }
  for (int b = tid; b < nbuck; b += 512) {
    int ex = (b == 0) ? 0 : scn[b - 1];
    lofs[b] = ex;
    cur[b]  = ex;
  }
  __syncthreads();

  // phase 2: scatter into LDS in bucket order + reserve global ranges
  for (int i = beg + tid; i < end; i += 512) {
    int r = rows[i];
    int b = r >> 7;
    int pos = atomicAdd(&cur[b], 1);
    buf[pos] = make_int2(((r & 127) << 17) | cols[i], __float_as_int(vals[i]));
    sb[pos]  = (unsigned short)b;
  }
  for (int b = tid; b < nbuck; b += 512)
    gbase[b] = h1[b] ? atomicAdd(&gcnt[b], h1[b]) : 0;
  __syncthreads();

  // phase 3: sequential write-out (coalesced runs)
  for (int i = tid; i < cnt; i += 512) {
    int b = sb[i];
    int pos = gbase[b] + (i - lofs[b]);
    int2 ed = buf[i];
    if (pos < BCAP) {
      binned[(size_t)b * BCAP + pos] = ed;
    } else {
      int k = atomicAdd(ovfN, 1);
      if (k < OVF_CAP) ovf[k] = make_int4(b, ed.x, ed.y, 0);
    }
  }
}

// ---------------- Row-sort each bucket + bucket-local CSR offsets ----------
__global__ __launch_bounds__(512) void bucket_sort(
    const int* __restrict__ gcnt, int2* __restrict__ binned,
    int* __restrict__ rowoff, int nbuck)
{
  __shared__ int2 buf[BCAP];
  __shared__ int hist[RPB];
  __shared__ int offs[RPB];
  __shared__ int cur[RPB];
  const int b = blockIdx.x, tid = threadIdx.x;
  const int cnt = min(gcnt[b], BCAP);
  int2* gp = binned + (size_t)b * BCAP;

  if (tid < RPB) hist[tid] = 0;
  __syncthreads();
  for (int i = tid; i < cnt; i += 512) {
    int2 e = gp[i];
    buf[i] = e;
    atomicAdd(&hist[e.x >> 17], 1);
  }
  __syncthreads();
  if (tid == 0) {
    int run = 0;
    for (int r = 0; r < RPB; ++r) { offs[r] = run; cur[r] = run; run += hist[r]; }
  }
  __syncthreads();
  if (tid < RPB) rowoff[b * RPB + tid] = offs[tid];
  for (int i = tid; i < cnt; i += 512) {
    int2 e = buf[i];
    int pos = atomicAdd(&cur[e.x >> 17], 1);
    gp[pos] = e;
  }
}

// ---------------- APPNP step: row-segment gather, batched edge preload -----
__global__ __launch_bounds__(256) void sorted_gather(
    const int* __restrict__ rowoff, const int* __restrict__ gcnt,
    const int2* __restrict__ binned, const float* __restrict__ Z,
    const float* __restrict__ Hin, float* __restrict__ Hout,
    const int4* __restrict__ ovf, const int* __restrict__ ovfN,
    float cB, int n)
{
  int g = blockIdx.x * 256 + threadIdx.x;
  int r = g >> 2, l = g & 3;
  if (r >= n) return;
  int b = r >> 7, rl = r & 127;
  int cntraw = gcnt[b];
  int cnt = min(cntraw, BCAP);
  int beg = rowoff[b * RPB + rl];
  int end = (rl == RPB - 1) ? cnt : rowoff[b * RPB + rl + 1];
  const int2* bp = binned + (size_t)b * BCAP;   // 16B-aligned
  float sx = 0.f, sy = 0.f;

  const int astart = (beg + 1) & ~1;
  if (l == 0 && beg < astart && beg < end) {
    int2 p0 = bp[beg];
    float v = __int_as_float(p0.y);
    float2 h = *reinterpret_cast<const float2*>(&Hin[(size_t)(p0.x & 0x1FFFF) * 2]);
    sx = fmaf(v, h.x, sx); sy = fmaf(v, h.y, sy);
  }
  int npair = (end > astart) ? ((end - astart) >> 1) : 0;
  if (l == 1 && end > astart && ((end - astart) & 1)) {
    int2 p0 = bp[end - 1];
    float v = __int_as_float(p0.y);
    float2 h = *reinterpret_cast<const float2*>(&Hin[(size_t)(p0.x & 0x1FFFF) * 2]);
    sx = fmaf(v, h.x, sx); sy = fmaf(v, h.y, sy);
  }
  const int4* bp4 = reinterpret_cast<const int4*>(bp) + (astart >> 1);

  int4 eb[8];
  #pragma unroll
  for (int c = 0; c < 8; ++c) {
    int k = l + 4 * c;
    if (k < npair) eb[c] = bp4[k];
  }
  #pragma unroll
  for (int c = 0; c < 8; ++c) {
    int k = l + 4 * c;
    if (k < npair) {
      int4 p = eb[c];
      float vA = __int_as_float(p.y), vB = __int_as_float(p.w);
      float2 hA = *reinterpret_cast<const float2*>(&Hin[(size_t)(p.x & 0x1FFFF) * 2]);
      float2 hB = *reinterpret_cast<const float2*>(&Hin[(size_t)(p.z & 0x1FFFF) * 2]);
      sx = fmaf(vA, hA.x, fmaf(vB, hB.x, sx));
      sy = fmaf(vA, hA.y, fmaf(vB, hB.y, sy));
    }
  }
  for (int k = l + 32; k < npair; k += 4) {     // deg > 64: ~never
    int4 p = bp4[k];
    float vA = __int_as_float(p.y), vB = __int_as_float(p.w);
    float2 hA = *reinterpret_cast<const float2*>(&Hin[(size_t)(p.x & 0x1FFFF) * 2]);
    float2 hB = *reinterpret_cast<const float2*>(&Hin[(size_t)(p.z & 0x1FFFF) * 2]);
    sx = fmaf(vA, hA.x, fmaf(vB, hB.x, sx));
    sy = fmaf(vA, hA.y, fmaf(vB, hB.y, sy));
  }

  if (cntraw > BCAP) {                          // statistically never
    int mo = min(*ovfN, OVF_CAP);
    for (int j = l; j < mo; j += 4) {
      int4 o = ovf[j];
      if (o.x == b && (o.y >> 17) == rl) {
        int col = o.y & 0x1FFFF;
        float v = __int_as_float(o.z);
        float2 h = *reinterpret_cast<const float2*>(&Hin[(size_t)col * 2]);
        sx += v * h.x; sy += v * h.y;
      }
    }
  }
  sx += __shfl_xor(sx, 1); sy += __shfl_xor(sy, 1);
  sx += __shfl_xor(sx, 2); sy += __shfl_xor(sy, 2);
  if (l == 0) {
    float2 z = *reinterpret_cast<const float2*>(&Z[(size_t)r * 2]);
    reinterpret_cast<float2*>(Hout)[r] =
        make_float2(ALPHA * z.x + cB * sx, ALPHA * z.y + cB * sy);
  }
}

extern "C" void kernel_launch(void* const* d_in, const int* in_sizes, int n_in,
                              void* d_out, int out_size, void* d_ws, size_t ws_size,
                              hipStream_t stream) {
  const float* x     = (const float*)d_in[0];
  const float* W1    = (const float*)d_in[1];
  const float* b1    = (const float*)d_in[2];
  const float* W2    = (const float*)d_in[3];
  const float* b2    = (const float*)d_in[4];
  const int*   erows = (const int*)d_in[5];
  const int*   ecols = (const int*)d_in[6];
  const float* evals = (const float*)d_in[7];
  float* out = (float*)d_out;

  const int n = in_sizes[0] / IN_DIM;     // 100000
  const int e = in_sizes[5];              // 3200000
  const int nbuck = (n + RPB - 1) / RPB;  // 782

  char* ws = (char*)d_ws;
  int2*  binned = (int2*)ws;            ws += (size_t)nbuck * BCAP * sizeof(int2);
  int4*  ovf    = (int4*)ws;            ws += (size_t)OVF_CAP * sizeof(int4);
  float* Z      = (float*)ws;           ws += (size_t)n * 2 * sizeof(float);
  float* Ha     = (float*)ws;           ws += (size_t)n * 2 * sizeof(float);
  float* Hb     = (float*)ws;           ws += (size_t)n * 2 * sizeof(float);
  unsigned short* W1F = (unsigned short*)ws;  ws += 2 * 16384 * sizeof(unsigned short);
  int*   rowoff = (int*)ws;             ws += (size_t)nbuck * RPB * sizeof(int);
  int*   gcnt   = (int*)ws;             ws += (size_t)nbuck * sizeof(int);
  int*   ovfN   = (int*)ws;             ws += 4 * sizeof(int);

  // w1_frag first: fuses gcnt/ovfN zeroing (stream-ordered before build2)
  w1_frag<<<64, 256, 0, stream>>>(W1, W1F, gcnt, ovfN, nbuck);

  const int grid_b = (e + CHUNK - 1) / CHUNK;   // 511
  bucket_build2<<<grid_b, 512, 0, stream>>>(erows, ecols, evals, gcnt,
                                            binned, ovf, ovfN, e, nbuck);
  bucket_sort<<<nbuck, 512, 0, stream>>>(gcnt, binned, rowoff, nbuck);

  mlp_mfma<<<(n + 63) / 64, 256, 0, stream>>>(x, W1F, b1, W2, b2, Z, n);

  const float cB = 1.f - ALPHA;
  const int grid_g = (4 * n + 255) / 256;
  const float* hin = Z;
  for (int t = 0; t < K_ITERS; ++t) {
    float* hout = (t == K_ITERS - 1) ? out : ((t & 1) ? Hb : Ha);
    sorted_gather<<<grid_g, 256, 0, stream>>>(rowoff, gcnt, binned, Z, hin, hout,
                                              ovf, ovfN, cB, n);
    hin = hout;
  }
}